// Round 11
// baseline (1438.996 us; speedup 1.0000x reference)
//
#include <hip/hip_runtime.h>
#include <hip/hip_bf16.h>
#include <hip/hip_fp16.h>

// ---------------------------------------------------------------------------
// MPSGNN: 4 metapath SAGE GNNs + metapath attention + MLP head.
// N_A=40000, N_B=80000, C=256, M=4, E=250000, heads=4 (d=64)
// Round 11: (1) multi-pass windowed fill (blockIdx.z = 8192-row dst window)
// to fix 109MB scattered-write amplification (140us -> ~40us predicted);
// (2) mgemm tile 64x128 -> 64x256 (barrier amortization). Math unchanged.
// ---------------------------------------------------------------------------

#define N_A 40000
#define N_B 80000
#define CDIM 256
#define MP 4
#define EDG 250000

using f16x8 = __attribute__((ext_vector_type(8))) _Float16;
using f32x4 = __attribute__((ext_vector_type(4))) float;

// ---- dtype helpers --------------------------------------------------------
__device__ __forceinline__ float ldf(const float* p) { return *p; }
__device__ __forceinline__ float ldf(const __half* p) { return __half2float(*p); }
__device__ __forceinline__ void stf(float* p, float v) { *p = v; }
__device__ __forceinline__ void stf(__half* p, float v) { *p = __float2half(v); }

__device__ __forceinline__ float4 ld4(const __half* p) {
    __half2 a = *(const __half2*)p, b = *(const __half2*)(p + 2);
    float2 fa = __half22float2(a), fb = __half22float2(b);
    return make_float4(fa.x, fa.y, fb.x, fb.y);
}

// ---------------- MFMA GEMM: C[M,N] = act(A[M,K] @ BT[N,K]^T + ...) --------
// Tile 64(M) x 256(N), BK=32, 256 threads = 4 waves (2x2), each wave 32x128.
// FUSE2: A is [x | A2] along K (both __half, lda/256), BT pre-concatenated.
template<typename AT, typename CT, typename ET, bool FUSE2, bool EXTRA,
         bool BIAS, bool RELU, bool OSCALE>
__global__ __launch_bounds__(256) void mgemm_k(
    const AT* __restrict__ A, int lda,
    const __half* __restrict__ A2,
    const __half* __restrict__ BT,
    const float* __restrict__ bias,
    const ET* __restrict__ extra, int lde,
    const float* __restrict__ osp, int osi,
    CT* __restrict__ C, int ldc, int K)
{
    __shared__ __align__(16) _Float16 As[64 * 40];    // [m][k], pad 40
    __shared__ __align__(16) _Float16 Bs[256 * 40];   // [n][k]
    const int tid = threadIdx.x;
    const int w = tid >> 6, lane = tid & 63;
    const int wm = w & 1, wn = w >> 1;
    const int lr = lane & 15, kb = lane >> 4;
    const long long row0 = (long long)blockIdx.y * 64;
    const int col0 = blockIdx.x * 256;
    f32x4 acc[2][8] = {};
    for (int k0 = 0; k0 < K; k0 += 32) {
        // stage A: 64 rows x 32 k (8 elems/thread)
        {
            int flat = tid * 8;
            int r = flat >> 5, c = flat & 31;
            int kk = k0 + c;
            if constexpr (FUSE2) {
                const __half* src = (kk < 256)
                    ? (const __half*)&A[(row0 + r) * lda + kk]
                    : &A2[(row0 + r) * 256 + (kk - 256)];
                *(f16x8*)&As[r * 40 + c] = *(const f16x8*)src;
            } else if constexpr (sizeof(AT) == 4) {
                const AT* src = &A[(row0 + r) * lda + kk];
                float4 v0 = *(const float4*)(src);
                float4 v1 = *(const float4*)(src + 4);
                _Float16 h[8] = {(_Float16)v0.x, (_Float16)v0.y, (_Float16)v0.z,
                                 (_Float16)v0.w, (_Float16)v1.x, (_Float16)v1.y,
                                 (_Float16)v1.z, (_Float16)v1.w};
                *(f16x8*)&As[r * 40 + c] = *(f16x8*)h;
            } else {
                *(f16x8*)&As[r * 40 + c] =
                    *(const f16x8*)&A[(row0 + r) * lda + kk];
            }
        }
        // stage B: 256 rows x 32 k from BT (4x 16B chunks/thread: row=tid)
        {
            #pragma unroll
            for (int q = 0; q < 4; ++q) {
                *(f16x8*)&Bs[tid * 40 + q * 8] =
                    *(const f16x8*)&BT[(long long)(col0 + tid) * K + k0 + q * 8];
            }
        }
        __syncthreads();
        f16x8 af[2], bf[8];
        #pragma unroll
        for (int i = 0; i < 2; ++i)
            af[i] = *(f16x8*)&As[(wm * 32 + i * 16 + lr) * 40 + kb * 8];
        #pragma unroll
        for (int j = 0; j < 8; ++j)
            bf[j] = *(f16x8*)&Bs[(wn * 128 + j * 16 + lr) * 40 + kb * 8];
        #pragma unroll
        for (int i = 0; i < 2; ++i)
            #pragma unroll
            for (int j = 0; j < 8; ++j)
                acc[i][j] = __builtin_amdgcn_mfma_f32_16x16x32_f16(
                    af[i], bf[j], acc[i][j], 0, 0, 0);
        __syncthreads();
    }
    float osc = 1.0f;
    if (OSCALE) osc = osp[osi];
    #pragma unroll
    for (int i = 0; i < 2; ++i) {
        #pragma unroll
        for (int j = 0; j < 8; ++j) {
            #pragma unroll
            for (int r = 0; r < 4; ++r) {
                long long rg = row0 + wm * 32 + i * 16 + (lane >> 4) * 4 + r;
                int cg = col0 + wn * 128 + j * 16 + (lane & 15);
                float v = acc[i][j][r];
                if (EXTRA) v += ldf(&extra[rg * lde + cg]);
                if (BIAS) v += bias[cg];
                if (RELU) v = fmaxf(v, 0.0f);
                if (OSCALE) v *= osc;
                stf(&C[rg * ldc + cg], v);
            }
        }
    }
}

// ---------------- input fp32 -> fp16 ---------------------------------------
__global__ void cvt8_k(const float* __restrict__ s, __half* __restrict__ d, int n8)
{
    int t = blockIdx.x * 256 + threadIdx.x;
    if (t >= n8) return;
    const float4 a = *(const float4*)&s[t * 8];
    const float4 b = *(const float4*)&s[t * 8 + 4];
    _Float16 h[8] = {(_Float16)a.x, (_Float16)a.y, (_Float16)a.z, (_Float16)a.w,
                     (_Float16)b.x, (_Float16)b.y, (_Float16)b.z, (_Float16)b.w};
    *(f16x8*)&d[t * 8] = *(f16x8*)h;
}

// ---------------- merged weight prep (7 sections via blockIdx.y) -----------
__global__ __launch_bounds__(256) void prep_k(
    const float* __restrict__ wl1, const float* __restrict__ wr1,
    const float* __restrict__ outw, const float* __restrict__ wr2,
    const float* __restrict__ wl2, const float* __restrict__ ipw,
    const float* __restrict__ aow, const float* __restrict__ m1w,
    const float* __restrict__ aob, const float* __restrict__ m1b,
    __half* __restrict__ WL1T, __half* __restrict__ WR1T,
    __half* __restrict__ OUTWT, __half* __restrict__ BT2,
    __half* __restrict__ IPW16, __half* __restrict__ WCT,
    float* __restrict__ BC)
{
    const int sec = blockIdx.y;
    const int t = blockIdx.x * 256 + threadIdx.x;
    if (sec < 3) {            // transposes: 4x[256][256], d[m][c][r]=s[m][r][c]
        if (t >= 262144) return;
        const float* s = (sec == 0) ? wl1 : (sec == 1) ? wr1 : outw;
        __half* d = (sec == 0) ? WL1T : (sec == 1) ? WR1T : OUTWT;
        int m = t >> 16, i = t & 65535, r = i >> 8, c = i & 255;
        d[(m << 16) + (c << 8) + r] = __float2half(s[t]);
    } else if (sec == 3) {    // BT2[m][n][k]: wr2 | wl2 transposed concat
        if (t >= 524288) return;
        int m = t >> 17, i = t & 131071, n = i >> 9, k = i & 511;
        float v = (k < 256) ? wr2[(m << 16) + (k << 8) + n]
                            : wl2[(m << 16) + ((k - 256) << 8) + n];
        BT2[t] = __float2half(v);
    } else if (sec == 4) {    // ipw flat copy-cast
        if (t >= 196608) return;
        IPW16[t] = __float2half(ipw[t]);
    } else if (sec == 5) {    // WcT[n][k] = sum_j aow[j][k]*m1w[j][n]
        if (t >= 65536) return;
        int n = t >> 8, k = t & 255;
        float s = 0.0f;
        for (int j = 0; j < 256; ++j)
            s = fmaf(aow[j * 256 + k], m1w[j * 256 + n], s);
        WCT[t] = __float2half(s);
    } else {                  // bc[n] = aob . m1w[:,n] + m1b[n]
        if (t >= 256) return;
        float s = m1b[t];
        for (int j = 0; j < 256; ++j) s = fmaf(aob[j], m1w[j * 256 + t], s);
        BC[t] = s;
    }
}

// ---------------- batched CSR build over 8 lists (blockIdx.y = list) -------
__global__ __launch_bounds__(256) void hist_all_k(
    const int* __restrict__ e_ab, const int* __restrict__ e_ba,
    int* __restrict__ cnt_all)
{
    const int l = blockIdx.y;
    const int e = blockIdx.x * 256 + threadIdx.x;
    if (e >= EDG) return;
    const int m = l >> 1, dir = l & 1;
    const int* dst = (dir ? e_ba : e_ab) + (size_t)m * 2 * EDG + EDG;
    atomicAdd(&cnt_all[l * 80000 + dst[e]], 1);
}
__global__ __launch_bounds__(256) void scan_blk_all_k(
    const int* __restrict__ cnt_all, int* __restrict__ bsum_all)
{
    __shared__ int s[256];
    const int l = blockIdx.y, t = threadIdx.x;
    const int i = blockIdx.x * 256 + t;
    s[t] = (i < 80000) ? cnt_all[l * 80000 + i] : 0;
    __syncthreads();
    for (int off = 128; off > 0; off >>= 1) {
        if (t < off) s[t] += s[t + off];
        __syncthreads();
    }
    if (t == 0) bsum_all[l * 313 + blockIdx.x] = s[0];
}
__global__ __launch_bounds__(512) void scan_top_all_k(
    const int* __restrict__ bsum_all, int* __restrict__ boff_all)
{
    __shared__ int s[512];
    const int l = blockIdx.x, t = threadIdx.x;
    int v = (t < 313) ? bsum_all[l * 313 + t] : 0;
    s[t] = v;
    __syncthreads();
    for (int off = 1; off < 512; off <<= 1) {
        int u = (t >= off) ? s[t - off] : 0;
        __syncthreads();
        s[t] += u;
        __syncthreads();
    }
    if (t < 313) boff_all[l * 313 + t] = s[t] - v;  // exclusive
}
__global__ __launch_bounds__(256) void scan_fin_all_k(
    const int* __restrict__ cnt_all, const int* __restrict__ boff_all,
    int* __restrict__ start_all, int* __restrict__ cursor_all)
{
    __shared__ int s[256];
    const int l = blockIdx.y, t = threadIdx.x;
    const int i = blockIdx.x * 256 + t;
    int v = (i < 80000) ? cnt_all[l * 80000 + i] : 0;
    s[t] = v;
    __syncthreads();
    for (int off = 1; off < 256; off <<= 1) {
        int u = (t >= off) ? s[t - off] : 0;
        __syncthreads();
        s[t] += u;
        __syncthreads();
    }
    if (i < 80000) {
        int ex = boff_all[l * 313 + blockIdx.x] + s[t] - v;
        start_all[l * 80000 + i] = ex;
        cursor_all[l * 80000 + i] = ex;
    }
}
// fill with dst-windowed passes: blockIdx.z = pass; window = 8192 dst rows.
// Active eidx write-window per pass ~100KB -> L2-resident, kills the 109MB
// scattered-write HBM amplification. Each edge commits in exactly one pass.
__global__ __launch_bounds__(256) void fill_all_k(
    const int* __restrict__ e_ab, const int* __restrict__ e_ba,
    int* __restrict__ cursor_all, int* __restrict__ eidx_all)
{
    const int l = blockIdx.y;
    const int pass = blockIdx.z;
    const int e = blockIdx.x * 256 + threadIdx.x;
    if (e >= EDG) return;
    const int m = l >> 1, dir = l & 1;
    const int* src = (dir ? e_ba : e_ab) + (size_t)m * 2 * EDG;
    const int* dst = src + EDG;
    const int d = dst[e];
    if ((d >> 13) != pass) return;
    int p = atomicAdd(&cursor_all[l * 80000 + d], 1);
    eidx_all[l * 250000 + p] = src[e];
}

// ---------------- gather-mean (fp16 in, fp16 out) --------------------------
__global__ __launch_bounds__(256) void gather_mean_k(
    const __half* __restrict__ feat, const int* __restrict__ start,
    const int* __restrict__ cnt, const int* __restrict__ eidx,
    __half* __restrict__ mean, int n)
{
    int t = blockIdx.x * 256 + threadIdx.x;
    int r = t >> 6, lane = t & 63;
    if (r >= n) return;
    const int s0 = start[r], deg = cnt[r];
    float4 acc = make_float4(0.f, 0.f, 0.f, 0.f);
    for (int i = 0; i < deg; ++i) {
        int s = eidx[s0 + i];
        float4 v = ld4(&feat[(long long)s * CDIM + lane * 4]);
        acc.x += v.x; acc.y += v.y; acc.z += v.z; acc.w += v.w;
    }
    const float inv = 1.0f / fmaxf((float)deg, 1.0f);
    __half hv[4] = {__float2half(acc.x * inv), __float2half(acc.y * inv),
                    __float2half(acc.z * inv), __float2half(acc.w * inv)};
    *(float2*)&mean[(long long)r * CDIM + lane * 4] = *(float2*)hv;
}

// ---------------- fused per-node attention + mean pool (fp16 in/out) -------
__global__ __launch_bounds__(256) void attn_pool_k(
    const __half* __restrict__ qkv, __half* __restrict__ pooled, int nNodes)
{
    __shared__ float sh[4][3072];
    __shared__ float sW[4][16];
    const int tid = threadIdx.x;
    const int wid = tid >> 6, lane = tid & 63;
    const int node = blockIdx.x * 4 + wid;   // nNodes % 4 == 0: never OOB
    float* S = sh[wid];
    const __half* base = qkv + (long long)node * 3072;
    #pragma unroll
    for (int it = 0; it < 6; ++it) {
        int f = it * 64 + lane;              // 0..383
        f16x8 v = *(const f16x8*)&base[f * 8];
        #pragma unroll
        for (int e = 0; e < 8; ++e) S[f * 8 + e] = (float)v[e];
    }
    __syncthreads();
    const int h = lane >> 4, qm = (lane >> 2) & 3, km = lane & 3;
    const float* qrow = &S[qm * 768 + h * 64];
    const float* krow = &S[km * 768 + 256 + h * 64];
    float s = 0.0f;
    #pragma unroll
    for (int i = 0; i < 64; ++i) s = fmaf(qrow[i], krow[i], s);
    s *= 0.125f;  // 1/sqrt(64)
    float mx = fmaxf(s, __shfl_xor(s, 1));
    mx = fmaxf(mx, __shfl_xor(mx, 2));
    float e = __expf(s - mx);
    float sum = e + __shfl_xor(e, 1);
    sum += __shfl_xor(sum, 2);
    float a = e / sum;
    float tt = a + __shfl_xor(a, 4);
    tt += __shfl_xor(tt, 8);
    if (qm == 0) sW[wid][h * 4 + km] = 0.25f * tt;
    __syncthreads();
    #pragma unroll
    for (int j = 0; j < 4; ++j) {
        int c = j * 64 + lane;
        float p = 0.0f;
        #pragma unroll
        for (int kk = 0; kk < 4; ++kk)
            p = fmaf(sW[wid][j * 4 + kk], S[kk * 768 + 512 + c], p);
        pooled[(long long)node * 256 + c] = __float2half(p);
    }
}

// ---------------- final: out[n] = h[n] . mlp2_w + mlp2_b -------------------
__global__ __launch_bounds__(256) void mlp2_k(
    const __half* __restrict__ h, const float* __restrict__ w,
    const float* __restrict__ b, float* __restrict__ out, int n)
{
    int t = blockIdx.x * 256 + threadIdx.x;
    int node = t >> 6, lane = t & 63;
    if (node >= n) return;
    const float4 hv = ld4(&h[(long long)node * CDIM + lane * 4]);
    const float4 wv = *(const float4*)&w[lane * 4];
    float s = hv.x * wv.x + hv.y * wv.y + hv.z * wv.z + hv.w * wv.w;
    #pragma unroll
    for (int off = 1; off < 64; off <<= 1) s += __shfl_xor(s, off);
    if (lane == 0) out[node] = s + b[0];
}

// ---------------- diagnostic fallback --------------------------------------
__global__ void diag_k(float* out, int n, float val)
{
    int t = blockIdx.x * 256 + threadIdx.x;
    if (t < n) out[t] = val;
}

// ---------------------------------------------------------------------------
extern "C" void kernel_launch(void* const* d_in, const int* in_sizes, int n_in,
                              void* d_out, int out_size, void* d_ws, size_t ws_size,
                              hipStream_t stream)
{
    const float* x_a  = (const float*)d_in[0];
    const float* x_b  = (const float*)d_in[1];
    const int*   e_ab = (const int*)d_in[2];
    const int*   e_ba = (const int*)d_in[3];
    const float* wl1  = (const float*)d_in[4];
    const float* wr1  = (const float*)d_in[5];
    const float* b1   = (const float*)d_in[6];
    const float* wl2  = (const float*)d_in[7];
    const float* wr2  = (const float*)d_in[8];
    const float* b2   = (const float*)d_in[9];
    const float* outw = (const float*)d_in[10];
    const float* outb = (const float*)d_in[11];
    const float* mpw  = (const float*)d_in[12];
    const float* ipw  = (const float*)d_in[13];  // [768,256]
    const float* ipb  = (const float*)d_in[14];  // [768]
    const float* aow  = (const float*)d_in[15];  // [256,256]
    const float* aob  = (const float*)d_in[16];
    const float* m1w  = (const float*)d_in[17];
    const float* m1b  = (const float*)d_in[18];
    const float* m2w  = (const float*)d_in[19];
    const float* m2b  = (const float*)d_in[20];
    float* out = (float*)d_out;

    // gate: NEED identical to rounds 4-10
    const size_t NEED = 40960000ull + 82240000ull + 40960000ull + 81920000ull
                      + 786432ull + 262144ull;   // 247,128,576
    if (ws_size < NEED || n_in < 21 || out_size != N_A) {
        float diag = (float)((ws_size / (1024ull * 1024ull)) * 100ull + (size_t)n_in);
        diag_k<<<(out_size + 255) / 256, 256, 0, stream>>>(out, out_size, diag);
        return;
    }

    // ---- layout (bytes): XA16 | XB16 | WH | AREG | BREG | EMBS | CSRALL ----
    char* base = (char*)d_ws;
    __half* XA16 = (__half*)(base);                    // 20,480,000
    __half* XB16 = (__half*)(base + 20480000);         // 40,960,000
    __half* WH   = (__half*)(base + 61440000);         //  4,194,304
    char*   AREG = base + 65634304;                    // 40,960,000
    char*   BREG = base + 106594304;                   // 40,960,000 (contig w/ AREG)
    __half* EMBS = (__half*)(base + 147554304);        // 81,920,000
    int*    CSR  = (int*)(base + 229474304);           // 15,700,032 (ends 245.2MB)
    // WH sublayout (halves)
    __half* WL1T  = WH;                  // 4x[256][256]
    __half* WR1T  = WH + 262144;
    __half* BT2   = WH + 524288;         // 4x[256][512] (wr2|wl2)
    __half* OUTWT = WH + 1048576;
    __half* IPW16 = WH + 1310720;        // [768][256]
    __half* WCT   = WH + 1507328;        // [256][256]
    float*  BC    = (float*)(WH + 1572864);
    // CSRALL sublayout (ints, uniform 80k stride per list, 8 lists)
    int* cnt_all    = CSR;               // 640,000
    int* start_all  = CSR + 640000;      // 640,000
    int* cursor_all = CSR + 1280000;     // 640,000
    int* eidx_all   = CSR + 1920000;     // 2,000,000
    int* bsum_all   = CSR + 3920000;     // 2,504
    int* boff_all   = CSR + 3922504;     // 2,504
    // rotating scratch (phase 1)
    __half* ZH      = (__half*)AREG;     // 20.48 MB
    __half* HBH     = (__half*)AREG;     // 40.96 MB (over ZH; ZH dead)
    __half* MEANB16 = (__half*)BREG;     // 40.96 MB
    __half* MEANA16 = (__half*)BREG;     // 20.48 MB (over MEANB; dead)
    __half* HA16    = (__half*)(BREG + 20480000);  // 20.48 MB
    // phase 2 overlays (AREG+BREG = contiguous 81.92 MB)
    __half* QKV16   = (__half*)AREG;               // 61.44 MB (CH=10000 chunk)
    __half* POOL16  = (__half*)(AREG + 61440000);  // 20.48 MB
    __half* TMLP16  = (__half*)AREG;               // 20.48 MB (QKV dead)

    // ---- conversions + weight prep (3 launches) ----
    cvt8_k<<<5000, 256, 0, stream>>>(x_a, XA16, 1280000);
    cvt8_k<<<10000, 256, 0, stream>>>(x_b, XB16, 2560000);
    prep_k<<<dim3(2048, 7), 256, 0, stream>>>(
        wl1, wr1, outw, wr2, wl2, ipw, aow, m1w, aob, m1b,
        WL1T, WR1T, OUTWT, BT2, IPW16, WCT, BC);

    // ---- batched CSR build for all 8 lists (6 launches) ----
    const int EB = (EDG + 255) / 256;    // 977
    hipMemsetAsync(cnt_all, 0, 640000 * 4, stream);
    hist_all_k<<<dim3(EB, 8), 256, 0, stream>>>(e_ab, e_ba, cnt_all);
    scan_blk_all_k<<<dim3(313, 8), 256, 0, stream>>>(cnt_all, bsum_all);
    scan_top_all_k<<<8, 512, 0, stream>>>(bsum_all, boff_all);
    scan_fin_all_k<<<dim3(313, 8), 256, 0, stream>>>(cnt_all, boff_all,
                                                     start_all, cursor_all);
    fill_all_k<<<dim3(EB, 8, 10), 256, 0, stream>>>(e_ab, e_ba, cursor_all,
                                                    eidx_all);

    // ---- metapath loop (6 launches per m) ----
    for (int m = 0; m < MP; ++m) {
        const int lB = 2 * m, lA = 2 * m + 1;
        // z = x_a @ wl1[m] -> ZH
        mgemm_k<__half, __half, float, false, false, false, false, false>
            <<<dim3(1, N_A / 64), 256, 0, stream>>>(
            XA16, CDIM, nullptr, WL1T + m * 65536, nullptr, nullptr, 0,
            nullptr, 0, ZH, CDIM, CDIM);
        // mean_b = gather-mean of z rows (CSR list lB)
        gather_mean_k<<<N_B / 4, 256, 0, stream>>>(
            ZH, start_all + lB * 80000, cnt_all + lB * 80000,
            eidx_all + lB * 250000, MEANB16, N_B);
        // h_b = relu(x_b @ wr1[m] + b1 + mean_b) -> HBH (over ZH; ZH dead)
        mgemm_k<__half, __half, __half, false, true, true, true, false>
            <<<dim3(1, N_B / 64), 256, 0, stream>>>(
            XB16, CDIM, nullptr, WR1T + m * 65536, b1 + (size_t)m * CDIM,
            MEANB16, CDIM, nullptr, 0, HBH, CDIM, CDIM);
        // mean_a = gather-mean of h_b rows (CSR list lA; over MEANB, dead)
        gather_mean_k<<<N_A / 4, 256, 0, stream>>>(
            HBH, start_all + lA * 80000, cnt_all + lA * 80000,
            eidx_all + lA * 250000, MEANA16, N_A);
        // h_a = relu([x_a | mean_a] @ [wr2;wl2]^T + b2)  (K=512 fused)
        mgemm_k<__half, __half, float, true, false, true, true, false>
            <<<dim3(1, N_A / 64), 256, 0, stream>>>(
            XA16, CDIM, MEANA16, BT2 + m * 131072, b2 + (size_t)m * CDIM,
            nullptr, 0, nullptr, 0, HA16, CDIM, 512);
        // embs[:,m,:] = (h_a @ outw[m] + outb[m]) * mpw[m]
        mgemm_k<__half, __half, float, false, false, true, false, true>
            <<<dim3(1, N_A / 64), 256, 0, stream>>>(
            HA16, CDIM, nullptr, OUTWT + m * 65536, outb + (size_t)m * CDIM,
            nullptr, 0, mpw, m, EMBS + (size_t)m * CDIM, 1024, CDIM);
    }

    // ---- phase 2: qkv (4 chunks of CH=10000) + fused attention/pool ----
    const int CH = 10000;
    for (int ch = 0; ch < N_A / CH; ++ch) {
        const int n0 = ch * CH;
        mgemm_k<__half, __half, float, false, false, true, false, false>
            <<<dim3(3, (CH * 4) / 64), 256, 0, stream>>>(
            EMBS + (size_t)n0 * 1024, CDIM, nullptr, IPW16, ipb, nullptr, 0,
            nullptr, 0, QKV16, 768, CDIM);
        attn_pool_k<<<CH / 4, 256, 0, stream>>>(
            QKV16, POOL16 + (size_t)n0 * 256, CH);
    }
    // tmlp = relu(pooled @ W_c + b_c)   (attn_out folded into mlp1)
    mgemm_k<__half, __half, float, false, false, true, true, false>
        <<<dim3(1, N_A / 64), 256, 0, stream>>>(
        POOL16, CDIM, nullptr, WCT, BC, nullptr, 0, nullptr, 0,
        TMLP16, CDIM, CDIM);
    mlp2_k<<<(N_A * 64) / 256, 256, 0, stream>>>(TMLP16, m2w, m2b, out, N_A);
}

// Round 14
// 1413.465 us; speedup vs baseline: 1.0181x; 1.0181x over previous
//
#include <hip/hip_runtime.h>
#include <hip/hip_bf16.h>
#include <hip/hip_fp16.h>

// ---------------------------------------------------------------------------
// MPSGNN: 4 metapath SAGE GNNs + metapath attention + MLP head.
// N_A=40000, N_B=80000, C=256, M=4, E=250000, heads=4 (d=64)
// Round 14: identical to rounds 12/13 (two GPU-acquisition timeouts; no data).
// Revert mgemm to 64x128 (64x256 regressed ~115us: tail imbalance);
// fill as per-(list,window) ownership blocks + LDS cursors ->
// contiguous eidx writes, zero global atomics. cursor_all deleted.
// ---------------------------------------------------------------------------

#define N_A 40000
#define N_B 80000
#define CDIM 256
#define MP 4
#define EDG 250000
#define FW 20        // windows per list
#define WROWS 4000   // 80000 / FW dst rows per window

using f16x8 = __attribute__((ext_vector_type(8))) _Float16;
using f32x4 = __attribute__((ext_vector_type(4))) float;

// ---- dtype helpers --------------------------------------------------------
__device__ __forceinline__ float ldf(const float* p) { return *p; }
__device__ __forceinline__ float ldf(const __half* p) { return __half2float(*p); }
__device__ __forceinline__ void stf(float* p, float v) { *p = v; }
__device__ __forceinline__ void stf(__half* p, float v) { *p = __float2half(v); }

__device__ __forceinline__ float4 ld4(const __half* p) {
    __half2 a = *(const __half2*)p, b = *(const __half2*)(p + 2);
    float2 fa = __half22float2(a), fb = __half22float2(b);
    return make_float4(fa.x, fa.y, fb.x, fb.y);
}

// ---------------- MFMA GEMM: C[M,N] = act(A[M,K] @ BT[N,K]^T + ...) --------
// Tile 64(M) x 128(N), BK=32, 256 threads = 4 waves (2x2), each wave 32x64.
// FUSE2: A is [x | A2] along K (both __half, lda/256), BT pre-concatenated.
template<typename AT, typename CT, typename ET, bool FUSE2, bool EXTRA,
         bool BIAS, bool RELU, bool OSCALE>
__global__ __launch_bounds__(256) void mgemm_k(
    const AT* __restrict__ A, int lda,
    const __half* __restrict__ A2,
    const __half* __restrict__ BT,
    const float* __restrict__ bias,
    const ET* __restrict__ extra, int lde,
    const float* __restrict__ osp, int osi,
    CT* __restrict__ C, int ldc, int K)
{
    __shared__ __align__(16) _Float16 As[64 * 40];   // [m][k], pad 40
    __shared__ __align__(16) _Float16 Bs[128 * 40];  // [n][k]
    const int tid = threadIdx.x;
    const int w = tid >> 6, lane = tid & 63;
    const int wm = w & 1, wn = w >> 1;
    const int lr = lane & 15, kb = lane >> 4;
    const long long row0 = (long long)blockIdx.y * 64;
    const int col0 = blockIdx.x * 128;
    f32x4 acc[2][4] = {};
    for (int k0 = 0; k0 < K; k0 += 32) {
        // stage A: 64 rows x 32 k (8 elems/thread)
        {
            int flat = tid * 8;
            int r = flat >> 5, c = flat & 31;
            int kk = k0 + c;
            if constexpr (FUSE2) {
                const __half* src = (kk < 256)
                    ? (const __half*)&A[(row0 + r) * lda + kk]
                    : &A2[(row0 + r) * 256 + (kk - 256)];
                *(f16x8*)&As[r * 40 + c] = *(const f16x8*)src;
            } else if constexpr (sizeof(AT) == 4) {
                const AT* src = &A[(row0 + r) * lda + kk];
                float4 v0 = *(const float4*)(src);
                float4 v1 = *(const float4*)(src + 4);
                _Float16 h[8] = {(_Float16)v0.x, (_Float16)v0.y, (_Float16)v0.z,
                                 (_Float16)v0.w, (_Float16)v1.x, (_Float16)v1.y,
                                 (_Float16)v1.z, (_Float16)v1.w};
                *(f16x8*)&As[r * 40 + c] = *(f16x8*)h;
            } else {
                *(f16x8*)&As[r * 40 + c] =
                    *(const f16x8*)&A[(row0 + r) * lda + kk];
            }
        }
        // stage B: 128 rows x 32 k from BT
        {
            #pragma unroll
            for (int q = 0; q < 2; ++q) {
                int cid = tid * 2 + q;
                int r = cid >> 2, cc = cid & 3;
                *(f16x8*)&Bs[r * 40 + cc * 8] =
                    *(const f16x8*)&BT[(long long)(col0 + r) * K + k0 + cc * 8];
            }
        }
        __syncthreads();
        f16x8 af[2], bf[4];
        #pragma unroll
        for (int i = 0; i < 2; ++i)
            af[i] = *(f16x8*)&As[(wm * 32 + i * 16 + lr) * 40 + kb * 8];
        #pragma unroll
        for (int j = 0; j < 4; ++j)
            bf[j] = *(f16x8*)&Bs[(wn * 64 + j * 16 + lr) * 40 + kb * 8];
        #pragma unroll
        for (int i = 0; i < 2; ++i)
            #pragma unroll
            for (int j = 0; j < 4; ++j)
                acc[i][j] = __builtin_amdgcn_mfma_f32_16x16x32_f16(
                    af[i], bf[j], acc[i][j], 0, 0, 0);
        __syncthreads();
    }
    float osc = 1.0f;
    if (OSCALE) osc = osp[osi];
    #pragma unroll
    for (int i = 0; i < 2; ++i) {
        #pragma unroll
        for (int j = 0; j < 4; ++j) {
            #pragma unroll
            for (int r = 0; r < 4; ++r) {
                long long rg = row0 + wm * 32 + i * 16 + (lane >> 4) * 4 + r;
                int cg = col0 + wn * 64 + j * 16 + (lane & 15);
                float v = acc[i][j][r];
                if (EXTRA) v += ldf(&extra[rg * lde + cg]);
                if (BIAS) v += bias[cg];
                if (RELU) v = fmaxf(v, 0.0f);
                if (OSCALE) v *= osc;
                stf(&C[rg * ldc + cg], v);
            }
        }
    }
}

// ---------------- input fp32 -> fp16 ---------------------------------------
__global__ void cvt8_k(const float* __restrict__ s, __half* __restrict__ d, int n8)
{
    int t = blockIdx.x * 256 + threadIdx.x;
    if (t >= n8) return;
    const float4 a = *(const float4*)&s[t * 8];
    const float4 b = *(const float4*)&s[t * 8 + 4];
    _Float16 h[8] = {(_Float16)a.x, (_Float16)a.y, (_Float16)a.z, (_Float16)a.w,
                     (_Float16)b.x, (_Float16)b.y, (_Float16)b.z, (_Float16)b.w};
    *(f16x8*)&d[t * 8] = *(f16x8*)h;
}

// ---------------- merged weight prep (7 sections via blockIdx.y) -----------
__global__ __launch_bounds__(256) void prep_k(
    const float* __restrict__ wl1, const float* __restrict__ wr1,
    const float* __restrict__ outw, const float* __restrict__ wr2,
    const float* __restrict__ wl2, const float* __restrict__ ipw,
    const float* __restrict__ aow, const float* __restrict__ m1w,
    const float* __restrict__ aob, const float* __restrict__ m1b,
    __half* __restrict__ WL1T, __half* __restrict__ WR1T,
    __half* __restrict__ OUTWT, __half* __restrict__ BT2,
    __half* __restrict__ IPW16, __half* __restrict__ WCT,
    float* __restrict__ BC)
{
    const int sec = blockIdx.y;
    const int t = blockIdx.x * 256 + threadIdx.x;
    if (sec < 3) {            // transposes: 4x[256][256], d[m][c][r]=s[m][r][c]
        if (t >= 262144) return;
        const float* s = (sec == 0) ? wl1 : (sec == 1) ? wr1 : outw;
        __half* d = (sec == 0) ? WL1T : (sec == 1) ? WR1T : OUTWT;
        int m = t >> 16, i = t & 65535, r = i >> 8, c = i & 255;
        d[(m << 16) + (c << 8) + r] = __float2half(s[t]);
    } else if (sec == 3) {    // BT2[m][n][k]: wr2 | wl2 transposed concat
        if (t >= 524288) return;
        int m = t >> 17, i = t & 131071, n = i >> 9, k = i & 511;
        float v = (k < 256) ? wr2[(m << 16) + (k << 8) + n]
                            : wl2[(m << 16) + ((k - 256) << 8) + n];
        BT2[t] = __float2half(v);
    } else if (sec == 4) {    // ipw flat copy-cast
        if (t >= 196608) return;
        IPW16[t] = __float2half(ipw[t]);
    } else if (sec == 5) {    // WcT[n][k] = sum_j aow[j][k]*m1w[j][n]
        if (t >= 65536) return;
        int n = t >> 8, k = t & 255;
        float s = 0.0f;
        for (int j = 0; j < 256; ++j)
            s = fmaf(aow[j * 256 + k], m1w[j * 256 + n], s);
        WCT[t] = __float2half(s);
    } else {                  // bc[n] = aob . m1w[:,n] + m1b[n]
        if (t >= 256) return;
        float s = m1b[t];
        for (int j = 0; j < 256; ++j) s = fmaf(aob[j], m1w[j * 256 + t], s);
        BC[t] = s;
    }
}

// ---------------- batched CSR build over 8 lists (blockIdx.y = list) -------
__global__ __launch_bounds__(256) void hist_all_k(
    const int* __restrict__ e_ab, const int* __restrict__ e_ba,
    int* __restrict__ cnt_all)
{
    const int l = blockIdx.y;
    const int e = blockIdx.x * 256 + threadIdx.x;
    if (e >= EDG) return;
    const int m = l >> 1, dir = l & 1;
    const int* dst = (dir ? e_ba : e_ab) + (size_t)m * 2 * EDG + EDG;
    atomicAdd(&cnt_all[l * 80000 + dst[e]], 1);
}
__global__ __launch_bounds__(256) void scan_blk_all_k(
    const int* __restrict__ cnt_all, int* __restrict__ bsum_all)
{
    __shared__ int s[256];
    const int l = blockIdx.y, t = threadIdx.x;
    const int i = blockIdx.x * 256 + t;
    s[t] = (i < 80000) ? cnt_all[l * 80000 + i] : 0;
    __syncthreads();
    for (int off = 128; off > 0; off >>= 1) {
        if (t < off) s[t] += s[t + off];
        __syncthreads();
    }
    if (t == 0) bsum_all[l * 313 + blockIdx.x] = s[0];
}
__global__ __launch_bounds__(512) void scan_top_all_k(
    const int* __restrict__ bsum_all, int* __restrict__ boff_all)
{
    __shared__ int s[512];
    const int l = blockIdx.x, t = threadIdx.x;
    int v = (t < 313) ? bsum_all[l * 313 + t] : 0;
    s[t] = v;
    __syncthreads();
    for (int off = 1; off < 512; off <<= 1) {
        int u = (t >= off) ? s[t - off] : 0;
        __syncthreads();
        s[t] += u;
        __syncthreads();
    }
    if (t < 313) boff_all[l * 313 + t] = s[t] - v;  // exclusive
}
__global__ __launch_bounds__(256) void scan_fin_all_k(
    const int* __restrict__ cnt_all, const int* __restrict__ boff_all,
    int* __restrict__ start_all)
{
    __shared__ int s[256];
    const int l = blockIdx.y, t = threadIdx.x;
    const int i = blockIdx.x * 256 + t;
    int v = (i < 80000) ? cnt_all[l * 80000 + i] : 0;
    s[t] = v;
    __syncthreads();
    for (int off = 1; off < 256; off <<= 1) {
        int u = (t >= off) ? s[t - off] : 0;
        __syncthreads();
        s[t] += u;
        __syncthreads();
    }
    if (i < 80000)
        start_all[l * 80000 + i] = boff_all[l * 313 + blockIdx.x] + s[t] - v;
}
// fill v2: one block OWNS one (list, window) pair. LDS cursors (no global
// atomics); eidx writes land in the window's contiguous region -> each line
// written by exactly one block on one XCD, flushed once.
__global__ __launch_bounds__(1024) void fill_win_k(
    const int* __restrict__ e_ab, const int* __restrict__ e_ba,
    const int* __restrict__ start_all, int* __restrict__ eidx_all)
{
    __shared__ int cur[WROWS];
    const int l = blockIdx.x, wdw = blockIdx.y;
    const int w0 = wdw * WROWS;
    for (int i = threadIdx.x; i < WROWS; i += 1024) cur[i] = 0;
    __syncthreads();
    const int m = l >> 1, dir = l & 1;
    const int* src = (dir ? e_ba : e_ab) + (size_t)m * 2 * EDG;
    const int* dst = src + EDG;
    const int* st = start_all + l * 80000;
    int* eidx = eidx_all + l * 250000;
    for (int e = threadIdx.x; e < EDG; e += 1024) {
        int d = dst[e];
        unsigned rel = (unsigned)(d - w0);
        if (rel < WROWS) {
            int p = atomicAdd(&cur[rel], 1);
            eidx[st[d] + p] = src[e];
        }
    }
}

// ---------------- gather-mean (fp16 in, fp16 out) --------------------------
__global__ __launch_bounds__(256) void gather_mean_k(
    const __half* __restrict__ feat, const int* __restrict__ start,
    const int* __restrict__ cnt, const int* __restrict__ eidx,
    __half* __restrict__ mean, int n)
{
    int t = blockIdx.x * 256 + threadIdx.x;
    int r = t >> 6, lane = t & 63;
    if (r >= n) return;
    const int s0 = start[r], deg = cnt[r];
    float4 acc = make_float4(0.f, 0.f, 0.f, 0.f);
    for (int i = 0; i < deg; ++i) {
        int s = eidx[s0 + i];
        float4 v = ld4(&feat[(long long)s * CDIM + lane * 4]);
        acc.x += v.x; acc.y += v.y; acc.z += v.z; acc.w += v.w;
    }
    const float inv = 1.0f / fmaxf((float)deg, 1.0f);
    __half hv[4] = {__float2half(acc.x * inv), __float2half(acc.y * inv),
                    __float2half(acc.z * inv), __float2half(acc.w * inv)};
    *(float2*)&mean[(long long)r * CDIM + lane * 4] = *(float2*)hv;
}

// ---------------- fused per-node attention + mean pool (fp16 in/out) -------
__global__ __launch_bounds__(256) void attn_pool_k(
    const __half* __restrict__ qkv, __half* __restrict__ pooled, int nNodes)
{
    __shared__ float sh[4][3072];
    __shared__ float sW[4][16];
    const int tid = threadIdx.x;
    const int wid = tid >> 6, lane = tid & 63;
    const int node = blockIdx.x * 4 + wid;   // nNodes % 4 == 0: never OOB
    float* S = sh[wid];
    const __half* base = qkv + (long long)node * 3072;
    #pragma unroll
    for (int it = 0; it < 6; ++it) {
        int f = it * 64 + lane;              // 0..383
        f16x8 v = *(const f16x8*)&base[f * 8];
        #pragma unroll
        for (int e = 0; e < 8; ++e) S[f * 8 + e] = (float)v[e];
    }
    __syncthreads();
    const int h = lane >> 4, qm = (lane >> 2) & 3, km = lane & 3;
    const float* qrow = &S[qm * 768 + h * 64];
    const float* krow = &S[km * 768 + 256 + h * 64];
    float s = 0.0f;
    #pragma unroll
    for (int i = 0; i < 64; ++i) s = fmaf(qrow[i], krow[i], s);
    s *= 0.125f;  // 1/sqrt(64)
    float mx = fmaxf(s, __shfl_xor(s, 1));
    mx = fmaxf(mx, __shfl_xor(mx, 2));
    float e = __expf(s - mx);
    float sum = e + __shfl_xor(e, 1);
    sum += __shfl_xor(sum, 2);
    float a = e / sum;
    float tt = a + __shfl_xor(a, 4);
    tt += __shfl_xor(tt, 8);
    if (qm == 0) sW[wid][h * 4 + km] = 0.25f * tt;
    __syncthreads();
    #pragma unroll
    for (int j = 0; j < 4; ++j) {
        int c = j * 64 + lane;
        float p = 0.0f;
        #pragma unroll
        for (int kk = 0; kk < 4; ++kk)
            p = fmaf(sW[wid][j * 4 + kk], S[kk * 768 + 512 + c], p);
        pooled[(long long)node * 256 + c] = __float2half(p);
    }
}

// ---------------- final: out[n] = h[n] . mlp2_w + mlp2_b -------------------
__global__ __launch_bounds__(256) void mlp2_k(
    const __half* __restrict__ h, const float* __restrict__ w,
    const float* __restrict__ b, float* __restrict__ out, int n)
{
    int t = blockIdx.x * 256 + threadIdx.x;
    int node = t >> 6, lane = t & 63;
    if (node >= n) return;
    const float4 hv = ld4(&h[(long long)node * CDIM + lane * 4]);
    const float4 wv = *(const float4*)&w[lane * 4];
    float s = hv.x * wv.x + hv.y * wv.y + hv.z * wv.z + hv.w * wv.w;
    #pragma unroll
    for (int off = 1; off < 64; off <<= 1) s += __shfl_xor(s, off);
    if (lane == 0) out[node] = s + b[0];
}

// ---------------- diagnostic fallback --------------------------------------
__global__ void diag_k(float* out, int n, float val)
{
    int t = blockIdx.x * 256 + threadIdx.x;
    if (t < n) out[t] = val;
}

// ---------------------------------------------------------------------------
extern "C" void kernel_launch(void* const* d_in, const int* in_sizes, int n_in,
                              void* d_out, int out_size, void* d_ws, size_t ws_size,
                              hipStream_t stream)
{
    const float* x_a  = (const float*)d_in[0];
    const float* x_b  = (const float*)d_in[1];
    const int*   e_ab = (const int*)d_in[2];
    const int*   e_ba = (const int*)d_in[3];
    const float* wl1  = (const float*)d_in[4];
    const float* wr1  = (const float*)d_in[5];
    const float* b1   = (const float*)d_in[6];
    const float* wl2  = (const float*)d_in[7];
    const float* wr2  = (const float*)d_in[8];
    const float* b2   = (const float*)d_in[9];
    const float* outw = (const float*)d_in[10];
    const float* outb = (const float*)d_in[11];
    const float* mpw  = (const float*)d_in[12];
    const float* ipw  = (const float*)d_in[13];  // [768,256]
    const float* ipb  = (const float*)d_in[14];  // [768]
    const float* aow  = (const float*)d_in[15];  // [256,256]
    const float* aob  = (const float*)d_in[16];
    const float* m1w  = (const float*)d_in[17];
    const float* m1b  = (const float*)d_in[18];
    const float* m2w  = (const float*)d_in[19];
    const float* m2b  = (const float*)d_in[20];
    float* out = (float*)d_out;

    // gate: NEED identical to rounds 4-13
    const size_t NEED = 40960000ull + 82240000ull + 40960000ull + 81920000ull
                      + 786432ull + 262144ull;   // 247,128,576
    if (ws_size < NEED || n_in < 21 || out_size != N_A) {
        float diag = (float)((ws_size / (1024ull * 1024ull)) * 100ull + (size_t)n_in);
        diag_k<<<(out_size + 255) / 256, 256, 0, stream>>>(out, out_size, diag);
        return;
    }

    // ---- layout (bytes): XA16 | XB16 | WH | AREG | BREG | EMBS | CSRALL ----
    char* base = (char*)d_ws;
    __half* XA16 = (__half*)(base);                    // 20,480,000
    __half* XB16 = (__half*)(base + 20480000);         // 40,960,000
    __half* WH   = (__half*)(base + 61440000);         //  4,194,304
    char*   AREG = base + 65634304;                    // 40,960,000
    char*   BREG = base + 106594304;                   // 40,960,000 (contig w/ AREG)
    __half* EMBS = (__half*)(base + 147554304);        // 81,920,000
    int*    CSR  = (int*)(base + 229474304);           // ends ~245 MB
    // WH sublayout (halves)
    __half* WL1T  = WH;                  // 4x[256][256]
    __half* WR1T  = WH + 262144;
    __half* BT2   = WH + 524288;         // 4x[256][512] (wr2|wl2)
    __half* OUTWT = WH + 1048576;
    __half* IPW16 = WH + 1310720;        // [768][256]
    __half* WCT   = WH + 1507328;        // [256][256]
    float*  BC    = (float*)(WH + 1572864);
    // CSRALL sublayout (ints, uniform 80k stride per list, 8 lists)
    int* cnt_all    = CSR;               // 640,000
    int* start_all  = CSR + 640000;      // 640,000
    int* eidx_all   = CSR + 1280000;     // 2,000,000
    int* bsum_all   = CSR + 3280000;     // 2,504
    int* boff_all   = CSR + 3282504;     // 2,504
    // rotating scratch (phase 1)
    __half* ZH      = (__half*)AREG;     // 20.48 MB
    __half* HBH     = (__half*)AREG;     // 40.96 MB (over ZH; ZH dead)
    __half* MEANB16 = (__half*)BREG;     // 40.96 MB
    __half* MEANA16 = (__half*)BREG;     // 20.48 MB (over MEANB; dead)
    __half* HA16    = (__half*)(BREG + 20480000);  // 20.48 MB
    // phase 2 overlays (AREG+BREG = contiguous 81.92 MB)
    __half* QKV16   = (__half*)AREG;               // 61.44 MB (CH=10000 chunk)
    __half* POOL16  = (__half*)(AREG + 61440000);  // 20.48 MB
    __half* TMLP16  = (__half*)AREG;               // 20.48 MB (QKV dead)

    // ---- conversions + weight prep (3 launches) ----
    cvt8_k<<<5000, 256, 0, stream>>>(x_a, XA16, 1280000);
    cvt8_k<<<10000, 256, 0, stream>>>(x_b, XB16, 2560000);
    prep_k<<<dim3(2048, 7), 256, 0, stream>>>(
        wl1, wr1, outw, wr2, wl2, ipw, aow, m1w, aob, m1b,
        WL1T, WR1T, OUTWT, BT2, IPW16, WCT, BC);

    // ---- batched CSR build for all 8 lists (6 launches) ----
    const int EB = (EDG + 255) / 256;    // 977
    hipMemsetAsync(cnt_all, 0, 640000 * 4, stream);
    hist_all_k<<<dim3(EB, 8), 256, 0, stream>>>(e_ab, e_ba, cnt_all);
    scan_blk_all_k<<<dim3(313, 8), 256, 0, stream>>>(cnt_all, bsum_all);
    scan_top_all_k<<<8, 512, 0, stream>>>(bsum_all, boff_all);
    scan_fin_all_k<<<dim3(313, 8), 256, 0, stream>>>(cnt_all, boff_all, start_all);
    fill_win_k<<<dim3(8, FW), 1024, 0, stream>>>(e_ab, e_ba, start_all, eidx_all);

    // ---- metapath loop (6 launches per m) ----
    for (int m = 0; m < MP; ++m) {
        const int lB = 2 * m, lA = 2 * m + 1;
        // z = x_a @ wl1[m] -> ZH
        mgemm_k<__half, __half, float, false, false, false, false, false>
            <<<dim3(2, N_A / 64), 256, 0, stream>>>(
            XA16, CDIM, nullptr, WL1T + m * 65536, nullptr, nullptr, 0,
            nullptr, 0, ZH, CDIM, CDIM);
        // mean_b = gather-mean of z rows (CSR list lB)
        gather_mean_k<<<N_B / 4, 256, 0, stream>>>(
            ZH, start_all + lB * 80000, cnt_all + lB * 80000,
            eidx_all + lB * 250000, MEANB16, N_B);
        // h_b = relu(x_b @ wr1[m] + b1 + mean_b) -> HBH (over ZH; ZH dead)
        mgemm_k<__half, __half, __half, false, true, true, true, false>
            <<<dim3(2, N_B / 64), 256, 0, stream>>>(
            XB16, CDIM, nullptr, WR1T + m * 65536, b1 + (size_t)m * CDIM,
            MEANB16, CDIM, nullptr, 0, HBH, CDIM, CDIM);
        // mean_a = gather-mean of h_b rows (CSR list lA; over MEANB, dead)
        gather_mean_k<<<N_A / 4, 256, 0, stream>>>(
            HBH, start_all + lA * 80000, cnt_all + lA * 80000,
            eidx_all + lA * 250000, MEANA16, N_A);
        // h_a = relu([x_a | mean_a] @ [wr2;wl2]^T + b2)  (K=512 fused)
        mgemm_k<__half, __half, float, true, false, true, true, false>
            <<<dim3(2, N_A / 64), 256, 0, stream>>>(
            XA16, CDIM, MEANA16, BT2 + m * 131072, b2 + (size_t)m * CDIM,
            nullptr, 0, nullptr, 0, HA16, CDIM, 512);
        // embs[:,m,:] = (h_a @ outw[m] + outb[m]) * mpw[m]
        mgemm_k<__half, __half, float, false, false, true, false, true>
            <<<dim3(2, N_A / 64), 256, 0, stream>>>(
            HA16, CDIM, nullptr, OUTWT + m * 65536, outb + (size_t)m * CDIM,
            nullptr, 0, mpw, m, EMBS + (size_t)m * CDIM, 1024, CDIM);
    }

    // ---- phase 2: qkv (4 chunks of CH=10000) + fused attention/pool ----
    const int CH = 10000;
    for (int ch = 0; ch < N_A / CH; ++ch) {
        const int n0 = ch * CH;
        mgemm_k<__half, __half, float, false, false, true, false, false>
            <<<dim3(6, (CH * 4) / 64), 256, 0, stream>>>(
            EMBS + (size_t)n0 * 1024, CDIM, nullptr, IPW16, ipb, nullptr, 0,
            nullptr, 0, QKV16, 768, CDIM);
        attn_pool_k<<<CH / 4, 256, 0, stream>>>(
            QKV16, POOL16 + (size_t)n0 * 256, CH);
    }
    // tmlp = relu(pooled @ W_c + b_c)   (attn_out folded into mlp1)
    mgemm_k<__half, __half, float, false, false, true, true, false>
        <<<dim3(2, N_A / 64), 256, 0, stream>>>(
        POOL16, CDIM, nullptr, WCT, BC, nullptr, 0, nullptr, 0,
        TMLP16, CDIM, CDIM);
    mlp2_k<<<(N_A * 64) / 256, 256, 0, stream>>>(TMLP16, m2w, m2b, out, N_A);
}